// Round 1
// baseline (4376.666 us; speedup 1.0000x reference)
//
#include <hip/hip_runtime.h>
#include <cstddef>

#define T_DIM 16384
#define B_DIM 4
#define RC 32
#define DC 32
#define COND 80
#define SC 256
#define CLASSES 256
#define TCH 16

// res0[b,c,t] = start_w[c] * x[b,t];  skip = 0
__global__ __launch_bounds__(512) void start_kernel(const float* __restrict__ x,
                                                    const float* __restrict__ sw,
                                                    float* __restrict__ res,
                                                    float* __restrict__ skip) {
    int idx = blockIdx.x * 512 + threadIdx.x;   // over B*RC*T = 2^21
    int t = idx & (T_DIM - 1);
    int c = (idx >> 14) & 31;
    int b = idx >> 19;
    float v = sw[c] * x[b * T_DIM + t];
    res[idx] = v;
    skip[idx] = 0.f;
}

// One thread per (b,t). Weight reads are wave-uniform -> scalar loads.
__global__ __launch_bounds__(256) void layer_kernel(
    const float* __restrict__ res_in,   // [B,32,T]
    float* __restrict__ res_out,        // [B,32,T]
    float* __restrict__ skip,           // [B,32,T] accumulated
    const float* __restrict__ h,        // [B,80,T]
    const float* __restrict__ dw,       // [32][32][2] this layer
    const float* __restrict__ fw,       // [32][32]
    const float* __restrict__ gw,       // [32][32]
    const float* __restrict__ cfw,      // [32][80]
    const float* __restrict__ cgw,      // [32][80]
    const float* __restrict__ ow)       // [32][32]
{
    int idx = blockIdx.x * 256 + threadIdx.x;   // over B*T
    int t = idx & (T_DIM - 1);
    int b = idx >> 14;
    const float* rb = res_in + (size_t)b * RC * T_DIM + t;
    const float* hb = h + (size_t)b * COND * T_DIM + t;

    // conditioning vector in registers (80 VGPRs)
    float hr[COND];
#pragma unroll
    for (int j = 0; j < COND; j++) hr[j] = hb[j * T_DIM];

    // y = causal dilated conv (K=2)
    float y[DC];
#pragma unroll
    for (int d = 0; d < DC; d++) y[d] = 0.f;

    for (int r = 0; r < RC; r++) {   // not unrolled: keeps code size small
        float cur = rb[r * T_DIM];
        float prv = (t > 0) ? rb[r * T_DIM - 1] : 0.f;
        const float* w2 = dw + r * 2;   // dw[(d*32+r)*2 + k]
#pragma unroll
        for (int d = 0; d < DC; d++) {
            y[d] = fmaf(w2[d * 64],     prv, y[d]);
            y[d] = fmaf(w2[d * 64 + 1], cur, y[d]);
        }
    }

    float outv[RC];
#pragma unroll
    for (int r = 0; r < RC; r++) outv[r] = 0.f;

    for (int d = 0; d < DC; d++) {   // not unrolled
        float fa = 0.f, ga = 0.f;
#pragma unroll
        for (int i = 0; i < DC; i++) {
            fa = fmaf(fw[d * DC + i], y[i], fa);
            ga = fmaf(gw[d * DC + i], y[i], ga);
        }
#pragma unroll
        for (int j = 0; j < COND; j++) {
            fa = fmaf(cfw[d * COND + j], hr[j], fa);
            ga = fmaf(cgw[d * COND + j], hr[j], ga);
        }
        // tanh via exp2-based __expf, clamped to avoid inf/inf
        float xc = fminf(fmaxf(fa, -15.f), 15.f);
        float e2v = __expf(2.f * xc);
        float th = (e2v - 1.f) / (e2v + 1.f);
        float sg = 1.f / (1.f + __expf(-ga));
        float z = th * sg;
#pragma unroll
        for (int r = 0; r < RC; r++) outv[r] = fmaf(ow[r * DC + d], z, outv[r]);
    }

    float* ro = res_out + (size_t)b * RC * T_DIM + t;
    float* sk = skip + (size_t)b * RC * T_DIM + t;
#pragma unroll
    for (int r = 0; r < RC; r++) {
        float o = outv[r];
        ro[r * T_DIM] = rb[r * T_DIM] + o;
        sk[r * T_DIM] += o;
    }
}

// end1 @ relu(skip) -> relu -> end2 ; per block: one (b, 16-wide t chunk)
__global__ __launch_bounds__(256) void end_kernel(
    const float* __restrict__ skip,   // [B,32,T]
    const float* __restrict__ e1,     // [256][32]
    const float* __restrict__ e2,     // [256][256]
    float* __restrict__ outp)         // [B][256][T]
{
    __shared__ float s_sk[RC][TCH];
    __shared__ float s_e[SC][TCH + 1];   // +1 pad: conflict-free writes

    int blk = blockIdx.x;               // B * (T/TCH)
    int b = blk / (T_DIM / TCH);
    int t0 = (blk % (T_DIM / TCH)) * TCH;
    int tid = threadIdx.x;

    for (int i = tid; i < RC * TCH; i += 256) {
        int c = i / TCH, p = i % TCH;
        s_sk[c][p] = fmaxf(skip[((size_t)b * RC + c) * T_DIM + t0 + p], 0.f);
    }
    __syncthreads();

    // phase 1: thread s computes e[s][0..15]
    {
        int s = tid;
        float acc[TCH];
#pragma unroll
        for (int p = 0; p < TCH; p++) acc[p] = 0.f;
        for (int c = 0; c < RC; c++) {
            float w = e1[s * RC + c];
#pragma unroll
            for (int p = 0; p < TCH; p++) acc[p] = fmaf(w, s_sk[c][p], acc[p]);
        }
#pragma unroll
        for (int p = 0; p < TCH; p++) s_e[s][p] = fmaxf(acc[p], 0.f);
    }
    __syncthreads();

    // phase 2: thread cls computes logit[cls][0..15]
    {
        int cls = tid;
        float acc[TCH];
#pragma unroll
        for (int p = 0; p < TCH; p++) acc[p] = 0.f;
        for (int s = 0; s < SC; s++) {
            float w = e2[cls * SC + s];
#pragma unroll
            for (int p = 0; p < TCH; p++) acc[p] = fmaf(w, s_e[s][p], acc[p]);
        }
        float* ob = outp + ((size_t)b * CLASSES + cls) * T_DIM + t0;
#pragma unroll
        for (int p = 0; p < TCH; p++) ob[p] = acc[p];
    }
}

extern "C" void kernel_launch(void* const* d_in, const int* in_sizes, int n_in,
                              void* d_out, int out_size, void* d_ws, size_t ws_size,
                              hipStream_t stream) {
    const float* x   = (const float*)d_in[0];
    const float* h   = (const float*)d_in[1];
    const float* sw  = (const float*)d_in[2];
    const float* dw  = (const float*)d_in[3];
    const float* fw  = (const float*)d_in[4];
    const float* gw  = (const float*)d_in[5];
    const float* cfw = (const float*)d_in[6];
    const float* cgw = (const float*)d_in[7];
    const float* ow  = (const float*)d_in[8];
    const float* e1  = (const float*)d_in[9];
    const float* e2  = (const float*)d_in[10];
    float* out = (float*)d_out;

    const size_t RES_N = (size_t)B_DIM * RC * T_DIM;   // 2,097,152 floats
    float* resA = (float*)d_ws;
    float* resB = resA + RES_N;
    float* skip = resB + RES_N;                        // total ~25 MB of ws

    start_kernel<<<(int)(RES_N / 512), 512, 0, stream>>>(x, sw, resA, skip);

    const float* rin = resA;
    float* rout = resB;
    for (int l = 0; l < 40; l++) {
        layer_kernel<<<(B_DIM * T_DIM) / 256, 256, 0, stream>>>(
            rin, rout, skip, h,
            dw + (size_t)l * DC * RC * 2,
            fw + (size_t)l * DC * DC,
            gw + (size_t)l * DC * DC,
            cfw + (size_t)l * DC * COND,
            cgw + (size_t)l * DC * COND,
            ow + (size_t)l * RC * DC);
        const float* tmp = rout;
        rout = (float*)rin;
        rin = tmp;
    }

    end_kernel<<<B_DIM * (T_DIM / TCH), 256, 0, stream>>>(skip, e1, e2, out);
}

// Round 2
// 4233.995 us; speedup vs baseline: 1.0337x; 1.0337x over previous
//
#include <hip/hip_runtime.h>
#include <cstddef>

#define T_DIM 16384
#define B_DIM 4
#define RC 32
#define DC 32
#define COND 80
#define SC 256
#define CLASSES 256
#define NLAYERS 40

#define TILE_W 128          // columns per block (= threads)
#define HALO NLAYERS        // 40: receptive field of 40 K=2 causal convs
#define TILE_OUT (TILE_W - HALO)              // 88 output columns
#define NT ((T_DIM + TILE_OUT - 1) / TILE_OUT) // 187 tiles per batch
#define TCH 16

// One-shot weight transposes into ws: e1T[c][s], e2T[s][cls], owT[l][d][r]
__global__ __launch_bounds__(256) void transpose_kernel(
    const float* __restrict__ e1, const float* __restrict__ e2,
    const float* __restrict__ ow,
    float* __restrict__ e1T, float* __restrict__ e2T, float* __restrict__ owT) {
    int idx = blockIdx.x * 256 + threadIdx.x;
    if (idx < SC * RC) {                       // e1: [s][c] -> e1T[c][s]
        int s = idx / RC, c = idx % RC;
        e1T[c * SC + s] = e1[idx];
    } else if (idx < SC * RC + CLASSES * SC) { // e2: [cls][s] -> e2T[s][cls]
        int t = idx - SC * RC;
        int cls = t / SC, s = t % SC;
        e2T[s * CLASSES + cls] = e2[t];
    } else {                                   // ow: [l][r][d] -> owT[l][d][r]
        int t = idx - SC * RC - CLASSES * SC;
        if (t < NLAYERS * RC * DC) {
            int l = t / (RC * DC), rem = t % (RC * DC);
            int r = rem / DC, d = rem % DC;
            owT[l * RC * DC + d * RC + r] = ow[t];
        }
    }
}

// All 40 layers fused. Block = one (b, t-tile); residual lives in LDS,
// h and skip live in registers. Halo-recompute, no inter-block comms.
__global__ __launch_bounds__(TILE_W, 2) void fused_layers_kernel(
    const float* __restrict__ x,    // [B,1,T]
    const float* __restrict__ h,    // [B,80,T]
    const float* __restrict__ sw,   // [32]
    const float* __restrict__ dw,   // [L][32][32][2]  (d, r, k)
    const float* __restrict__ fw,   // [L][32][32]
    const float* __restrict__ gw,   // [L][32][32]
    const float* __restrict__ cfw,  // [L][32][80]
    const float* __restrict__ cgw,  // [L][32][80]
    const float* __restrict__ owT,  // [L][32(d)][32(r)]  transposed
    float* __restrict__ skip_out)   // [B,32,T]
{
    __shared__ float res_s[RC][TILE_W];   // 16 KB

    const int tid = threadIdx.x;
    const int b = blockIdx.x / NT;
    const int tile = blockIdx.x % NT;
    const int gt = tile * TILE_OUT - HALO + tid;   // global t of this column
    const bool valid_in = (gt >= 0) && (gt < T_DIM);
    const int gtc = min(max(gt, 0), T_DIM - 1);

    // conditioning vector: register-resident for the whole kernel (80 VGPRs)
    const float* hb = h + (size_t)b * COND * T_DIM + gtc;
    float hr[COND];
#pragma unroll
    for (int j = 0; j < COND; j++) hr[j] = hb[j * T_DIM];

    // start 1x1 conv
    float xv = valid_in ? x[(size_t)b * T_DIM + gt] : 0.f;
#pragma unroll
    for (int c = 0; c < RC; c++) res_s[c][tid] = sw[c] * xv;

    float skipv[RC];
#pragma unroll
    for (int r = 0; r < RC; r++) skipv[r] = 0.f;
    __syncthreads();

    for (int l = 0; l < NLAYERS; l++) {
        const float* dwl  = dw  + (size_t)l * DC * RC * 2;
        const float* fwl  = fw  + (size_t)l * DC * DC;
        const float* gwl  = gw  + (size_t)l * DC * DC;
        const float* cfwl = cfw + (size_t)l * DC * COND;
        const float* cgwl = cgw + (size_t)l * DC * COND;
        const float* owl  = owT + (size_t)l * DC * RC;

        // phase A: causal conv (K=2). cur/prv from LDS, weights contiguous.
        float cur[RC], prv[RC];
#pragma unroll
        for (int r = 0; r < RC; r++) {
            cur[r] = res_s[r][tid];
            prv[r] = (tid > 0) ? res_s[r][tid - 1] : 0.f;
        }
        float y[DC];
        for (int d = 0; d < DC; d++) {
            const float* w = dwl + d * RC * 2;   // [r][k] contiguous
            float a = 0.f;
#pragma unroll
            for (int r = 0; r < RC; r++) {
                a = fmaf(w[2 * r],     prv[r], a);
                a = fmaf(w[2 * r + 1], cur[r], a);
            }
            y[d] = a;
        }

        // phase B: gated unit + output 1x1
        float outv[RC];
#pragma unroll
        for (int r = 0; r < RC; r++) outv[r] = 0.f;

        for (int d = 0; d < DC; d++) {
            const float* fr  = fwl  + d * DC;
            const float* gr  = gwl  + d * DC;
            const float* cfr = cfwl + d * COND;
            const float* cgr = cgwl + d * COND;
            float fa = 0.f, ga = 0.f;
#pragma unroll
            for (int i = 0; i < DC; i++) {
                fa = fmaf(fr[i], y[i], fa);
                ga = fmaf(gr[i], y[i], ga);
            }
#pragma unroll
            for (int j = 0; j < COND; j++) {
                fa = fmaf(cfr[j], hr[j], fa);
                ga = fmaf(cgr[j], hr[j], ga);
            }
            float xc  = fminf(fmaxf(fa, -15.f), 15.f);
            float e2v = __expf(2.f * xc);
            float th  = 1.f - 2.f / (e2v + 1.f);
            float sg  = 1.f / (1.f + __expf(-ga));
            float z   = th * sg;
            const float* owr = owl + d * RC;     // contiguous in r
#pragma unroll
            for (int r = 0; r < RC; r++) outv[r] = fmaf(owr[r], z, outv[r]);
        }

        // phase C: residual update in LDS, skip accumulate in regs
        __syncthreads();
#pragma unroll
        for (int r = 0; r < RC; r++) {
            float nv = res_s[r][tid] + outv[r];
            res_s[r][tid] = (gt < 0) ? 0.f : nv;   // zero the pre-t=0 pad
            skipv[r] += outv[r];
        }
        __syncthreads();
    }

    // only the 88 non-halo columns store skip
    if (tid >= HALO && gt < T_DIM) {
        float* sk = skip_out + (size_t)b * RC * T_DIM + gt;
#pragma unroll
        for (int r = 0; r < RC; r++) sk[r * T_DIM] = skipv[r];
    }
}

// end1 @ relu(skip) -> relu -> end2, with transposed (coalesced) weights
__global__ __launch_bounds__(256) void end_kernel(
    const float* __restrict__ skip,   // [B,32,T]
    const float* __restrict__ e1T,    // [32][256]
    const float* __restrict__ e2T,    // [256][256]
    float* __restrict__ outp)         // [B][256][T]
{
    __shared__ float s_sk[RC][TCH];
    __shared__ float s_e[SC][TCH + 1];

    int blk = blockIdx.x;
    int b = blk / (T_DIM / TCH);
    int t0 = (blk % (T_DIM / TCH)) * TCH;
    int tid = threadIdx.x;

    for (int i = tid; i < RC * TCH; i += 256) {
        int c = i / TCH, p = i % TCH;
        s_sk[c][p] = fmaxf(skip[((size_t)b * RC + c) * T_DIM + t0 + p], 0.f);
    }
    __syncthreads();

    {   // thread s computes e[s][0..15]; e1T load coalesced over lanes
        int s = tid;
        float acc[TCH];
#pragma unroll
        for (int p = 0; p < TCH; p++) acc[p] = 0.f;
        for (int c = 0; c < RC; c++) {
            float w = e1T[c * SC + s];
#pragma unroll
            for (int p = 0; p < TCH; p++) acc[p] = fmaf(w, s_sk[c][p], acc[p]);
        }
#pragma unroll
        for (int p = 0; p < TCH; p++) s_e[s][p] = fmaxf(acc[p], 0.f);
    }
    __syncthreads();

    {   // thread cls computes logit[cls][0..15]; e2T load coalesced
        int cls = tid;
        float acc[TCH];
#pragma unroll
        for (int p = 0; p < TCH; p++) acc[p] = 0.f;
        for (int s = 0; s < SC; s++) {
            float w = e2T[s * CLASSES + cls];
#pragma unroll
            for (int p = 0; p < TCH; p++) acc[p] = fmaf(w, s_e[s][p], acc[p]);
        }
        float* ob = outp + ((size_t)b * CLASSES + cls) * T_DIM + t0;
#pragma unroll
        for (int p = 0; p < TCH; p++) ob[p] = acc[p];
    }
}

extern "C" void kernel_launch(void* const* d_in, const int* in_sizes, int n_in,
                              void* d_out, int out_size, void* d_ws, size_t ws_size,
                              hipStream_t stream) {
    const float* x   = (const float*)d_in[0];
    const float* h   = (const float*)d_in[1];
    const float* sw  = (const float*)d_in[2];
    const float* dw  = (const float*)d_in[3];
    const float* fw  = (const float*)d_in[4];
    const float* gw  = (const float*)d_in[5];
    const float* cfw = (const float*)d_in[6];
    const float* cgw = (const float*)d_in[7];
    const float* ow  = (const float*)d_in[8];
    const float* e1  = (const float*)d_in[9];
    const float* e2  = (const float*)d_in[10];
    float* out = (float*)d_out;

    const size_t SKIP_N = (size_t)B_DIM * RC * T_DIM;   // 2,097,152 floats
    float* skip = (float*)d_ws;
    float* e1T  = skip + SKIP_N;
    float* e2T  = e1T + SC * RC;
    float* owT  = e2T + (size_t)CLASSES * SC;

    {   // transpose weights (e1, e2, ow)
        int total = SC * RC + CLASSES * SC + NLAYERS * RC * DC;
        transpose_kernel<<<(total + 255) / 256, 256, 0, stream>>>(
            e1, e2, ow, e1T, e2T, owT);
    }

    fused_layers_kernel<<<B_DIM * NT, TILE_W, 0, stream>>>(
        x, h, sw, dw, fw, gw, cfw, cgw, owT, skip);

    end_kernel<<<B_DIM * (T_DIM / TCH), 256, 0, stream>>>(skip, e1T, e2T, out);
}

// Round 3
// 2276.261 us; speedup vs baseline: 1.9227x; 1.8601x over previous
//
#include <hip/hip_runtime.h>
#include <cstddef>

#define T_DIM 16384
#define B_DIM 4
#define RC 32
#define DC 32
#define COND 80
#define SC 256
#define CLASSES 256
#define NLAYERS 40

#define TILE_W 128
#define TILE_OUT 64
#define HALO 64            // left halo (> 40-layer receptive field)
#define NT 256             // tiles per batch: 256*64 = 16384 exactly
#define TCH 16

#define WPL 10240          // packed weights per layer (floats)
// per-layer packed offsets
#define OFF_DW 0           // [r][k][d]  2048
#define OFF_FW 2048        // [i][d]     1024
#define OFF_GW 3072        // [i][d]     1024
#define OFF_CF 4096        // [j][d]     2560
#define OFF_CG 6656        // [j][d]     2560
#define OFF_OW 9216        // [d][r]     1024

// ---- weight repack: all matrices transposed so accumulator idx is contiguous
__global__ __launch_bounds__(256) void transpose_kernel(
    const float* __restrict__ dw, const float* __restrict__ fw,
    const float* __restrict__ gw, const float* __restrict__ cfw,
    const float* __restrict__ cgw, const float* __restrict__ ow,
    const float* __restrict__ e1, const float* __restrict__ e2,
    float* __restrict__ wAll, float* __restrict__ e1T, float* __restrict__ e2T)
{
    int idx = blockIdx.x * 256 + threadIdx.x;   // 483,328 total
    if (idx < NLAYERS * WPL) {
        int l = idx / WPL, o = idx % WPL;
        float v;
        if (o < OFF_FW) {            // dwT[r][k][d] <- dw[l][d][r][k]
            int r = o >> 6, k = (o >> 5) & 1, d = o & 31;
            v = dw[((l * 32 + d) * 32 + r) * 2 + k];
        } else if (o < OFF_GW) {     // fwT[i][d] <- fw[l][d][i]
            int i = (o - OFF_FW) >> 5, d = o & 31;
            v = fw[(l * 32 + d) * 32 + i];
        } else if (o < OFF_CF) {     // gwT
            int i = (o - OFF_GW) >> 5, d = o & 31;
            v = gw[(l * 32 + d) * 32 + i];
        } else if (o < OFF_CG) {     // cfT[j][d] <- cfw[l][d][j]
            int j = (o - OFF_CF) >> 5, d = o & 31;
            v = cfw[(l * 32 + d) * 80 + j];
        } else if (o < OFF_OW) {     // cgT
            int j = (o - OFF_CG) >> 5, d = o & 31;
            v = cgw[(l * 32 + d) * 80 + j];
        } else {                     // owT[d][r] <- ow[l][r][d]
            int d = (o - OFF_OW) >> 5, r = o & 31;
            v = ow[(l * 32 + r) * 32 + d];
        }
        wAll[idx] = v;
    } else if (idx < NLAYERS * WPL + RC * SC) {
        int t = idx - NLAYERS * WPL;              // e1T[c][s] <- e1[s][c]
        int c = t >> 8, s = t & 255;
        e1T[t] = e1[s * RC + c];
    } else {
        int t = idx - NLAYERS * WPL - RC * SC;    // e2T[s][cls] <- e2[cls][s]
        if (t < SC * CLASSES) {
            int s = t >> 8, cls = t & 255;
            e2T[t] = e2[cls * SC + s];
        }
    }
}

// ---- all 40 layers fused; res in LDS(fp32), h in LDS(bf16), skip = resL-res0
__global__ __launch_bounds__(128, 2) void fused_layers_kernel(
    const float* __restrict__ x,    // [B,1,T]
    const float* __restrict__ h,    // [B,80,T]
    const float* __restrict__ sw,   // [32]
    const float* __restrict__ wAll, // packed transposed weights [L][10240]
    float* __restrict__ skip_out)   // [B,32,T]
{
    __shared__ float res_s[RC][TILE_W];            // 16 KB
    __shared__ unsigned short h_s[COND][TILE_W];   // 20 KB bf16

    const int tid = threadIdx.x;
    const int b = blockIdx.x >> 8;
    const int tile = blockIdx.x & 255;
    const int gt = tile * TILE_OUT - HALO + tid;
    const bool live = (gt >= 0);
    const int gtc = min(max(gt, 0), T_DIM - 1);

    // stage conditioning as bf16 (RNE)
    const float* hb = h + (size_t)b * COND * T_DIM + gtc;
#pragma unroll 4
    for (int j = 0; j < COND; j++) {
        unsigned u = __float_as_uint(hb[(size_t)j * T_DIM]);
        unsigned r = (u + 0x7FFF + ((u >> 16) & 1)) >> 16;
        h_s[j][tid] = (unsigned short)r;
    }

    const float xv = live ? x[(size_t)b * T_DIM + gt] : 0.f;
#pragma unroll
    for (int c = 0; c < RC; c++) res_s[c][tid] = sw[c] * xv;
    __syncthreads();

    const float* wl = wAll;
#pragma unroll 1
    for (int l = 0; l < NLAYERS; ++l, wl += WPL) {
        // ---- A: causal K=2 conv, r-outer, y[32] accumulators
        float y[DC];
#pragma unroll
        for (int d = 0; d < DC; d++) y[d] = 0.f;
#pragma unroll 2
        for (int r = 0; r < RC; r++) {
            float cur = res_s[r][tid];
            float prv = (tid > 0) ? res_s[r][tid - 1] : 0.f;
            const float* w0 = wl + OFF_DW + r * 64;
#pragma unroll
            for (int d = 0; d < DC; d++) y[d] = fmaf(w0[d], prv, y[d]);
#pragma unroll
            for (int d = 0; d < DC; d++) y[d] = fmaf(w0[32 + d], cur, y[d]);
        }
        // ---- B1: f/g contributions from y, i-outer
        float pf[DC], pg[DC];
#pragma unroll
        for (int d = 0; d < DC; d++) { pf[d] = 0.f; pg[d] = 0.f; }
#pragma unroll 2
        for (int i = 0; i < DC; i++) {
            float yi = y[i];
            const float* wf = wl + OFF_FW + i * 32;
            const float* wg = wl + OFF_GW + i * 32;
#pragma unroll
            for (int d = 0; d < DC; d++) pf[d] = fmaf(wf[d], yi, pf[d]);
#pragma unroll
            for (int d = 0; d < DC; d++) pg[d] = fmaf(wg[d], yi, pg[d]);
        }
        // ---- B2: conditioning, j-outer, h from LDS
#pragma unroll 2
        for (int j = 0; j < COND; j++) {
            float hj = __uint_as_float(((unsigned)h_s[j][tid]) << 16);
            const float* cf = wl + OFF_CF + j * 32;
            const float* cg = wl + OFF_CG + j * 32;
#pragma unroll
            for (int d = 0; d < DC; d++) pf[d] = fmaf(cf[d], hj, pf[d]);
#pragma unroll
            for (int d = 0; d < DC; d++) pg[d] = fmaf(cg[d], hj, pg[d]);
        }
        // ---- B3 + out 1x1, d-outer
        float outv[RC];
#pragma unroll
        for (int r2 = 0; r2 < RC; r2++) outv[r2] = 0.f;
#pragma unroll 2
        for (int d = 0; d < DC; d++) {
            float xc = fminf(fmaxf(pf[d], -15.f), 15.f);
            float e2v = __expf(2.f * xc);
            float th = 1.f - 2.f / (e2v + 1.f);
            float sg = 1.f / (1.f + __expf(-pg[d]));
            float z = th * sg;
            const float* owd = wl + OFF_OW + d * 32;
#pragma unroll
            for (int r2 = 0; r2 < RC; r2++) outv[r2] = fmaf(owd[r2], z, outv[r2]);
        }
        // ---- C: residual update
        __syncthreads();
#pragma unroll
        for (int r2 = 0; r2 < RC; r2++) {
            float nv = res_s[r2][tid] + outv[r2];
            res_s[r2][tid] = live ? nv : 0.f;
        }
        __syncthreads();
    }

    // epilogue: skip = res_final - res_0
    if (tid >= HALO) {
        float* sk = skip_out + (size_t)b * RC * T_DIM + gt;
#pragma unroll
        for (int r2 = 0; r2 < RC; r2++)
            sk[(size_t)r2 * T_DIM] = res_s[r2][tid] - sw[r2] * xv;
    }
}

// ---- end: relu->e1->relu->e2, 64B LDS rows, float4 broadcast reads
__global__ __launch_bounds__(256) void end_kernel(
    const float* __restrict__ skip,   // [B,32,T]
    const float* __restrict__ e1T,    // [32][256]
    const float* __restrict__ e2T,    // [256][256]
    float* __restrict__ outp)         // [B][256][T]
{
    __shared__ float s_sk[RC][TCH];   // 2 KB, 64 B rows
    __shared__ float s_e[SC][TCH];    // 16 KB, 64 B rows

    const int blk = blockIdx.x;                 // 4096
    const int b = blk >> 10;
    const int t0 = (blk & 1023) * TCH;
    const int tid = threadIdx.x;

    if (tid < 128) {                            // 32 ch x 4 float4
        int c = tid >> 2, q = tid & 3;
        const float* sp = skip + ((size_t)b * RC + c) * T_DIM + t0 + q * 4;
        float4 v = *(const float4*)sp;
        v.x = fmaxf(v.x, 0.f); v.y = fmaxf(v.y, 0.f);
        v.z = fmaxf(v.z, 0.f); v.w = fmaxf(v.w, 0.f);
        *(float4*)&s_sk[c][q * 4] = v;
    }
    __syncthreads();

    float acc[TCH];
#pragma unroll
    for (int p = 0; p < TCH; p++) acc[p] = 0.f;
    {   // phase 1: thread = s
        const int s = tid;
#pragma unroll 2
        for (int c = 0; c < RC; c++) {
            float w = e1T[c * SC + s];
            const float4* row = (const float4*)&s_sk[c][0];
            float4 k0 = row[0], k1 = row[1], k2 = row[2], k3 = row[3];
            acc[0]  = fmaf(w, k0.x, acc[0]);  acc[1]  = fmaf(w, k0.y, acc[1]);
            acc[2]  = fmaf(w, k0.z, acc[2]);  acc[3]  = fmaf(w, k0.w, acc[3]);
            acc[4]  = fmaf(w, k1.x, acc[4]);  acc[5]  = fmaf(w, k1.y, acc[5]);
            acc[6]  = fmaf(w, k1.z, acc[6]);  acc[7]  = fmaf(w, k1.w, acc[7]);
            acc[8]  = fmaf(w, k2.x, acc[8]);  acc[9]  = fmaf(w, k2.y, acc[9]);
            acc[10] = fmaf(w, k2.z, acc[10]); acc[11] = fmaf(w, k2.w, acc[11]);
            acc[12] = fmaf(w, k3.x, acc[12]); acc[13] = fmaf(w, k3.y, acc[13]);
            acc[14] = fmaf(w, k3.z, acc[14]); acc[15] = fmaf(w, k3.w, acc[15]);
        }
        float4 o0 = make_float4(fmaxf(acc[0],0.f),  fmaxf(acc[1],0.f),
                                fmaxf(acc[2],0.f),  fmaxf(acc[3],0.f));
        float4 o1 = make_float4(fmaxf(acc[4],0.f),  fmaxf(acc[5],0.f),
                                fmaxf(acc[6],0.f),  fmaxf(acc[7],0.f));
        float4 o2 = make_float4(fmaxf(acc[8],0.f),  fmaxf(acc[9],0.f),
                                fmaxf(acc[10],0.f), fmaxf(acc[11],0.f));
        float4 o3 = make_float4(fmaxf(acc[12],0.f), fmaxf(acc[13],0.f),
                                fmaxf(acc[14],0.f), fmaxf(acc[15],0.f));
        float4* er = (float4*)&s_e[s][0];
        er[0] = o0; er[1] = o1; er[2] = o2; er[3] = o3;
    }
    __syncthreads();

#pragma unroll
    for (int p = 0; p < TCH; p++) acc[p] = 0.f;
    {   // phase 2: thread = cls
        const int cls = tid;
#pragma unroll 2
        for (int s2 = 0; s2 < SC; s2++) {
            float w = e2T[s2 * CLASSES + cls];
            const float4* row = (const float4*)&s_e[s2][0];
            float4 k0 = row[0], k1 = row[1], k2 = row[2], k3 = row[3];
            acc[0]  = fmaf(w, k0.x, acc[0]);  acc[1]  = fmaf(w, k0.y, acc[1]);
            acc[2]  = fmaf(w, k0.z, acc[2]);  acc[3]  = fmaf(w, k0.w, acc[3]);
            acc[4]  = fmaf(w, k1.x, acc[4]);  acc[5]  = fmaf(w, k1.y, acc[5]);
            acc[6]  = fmaf(w, k1.z, acc[6]);  acc[7]  = fmaf(w, k1.w, acc[7]);
            acc[8]  = fmaf(w, k2.x, acc[8]);  acc[9]  = fmaf(w, k2.y, acc[9]);
            acc[10] = fmaf(w, k2.z, acc[10]); acc[11] = fmaf(w, k2.w, acc[11]);
            acc[12] = fmaf(w, k3.x, acc[12]); acc[13] = fmaf(w, k3.y, acc[13]);
            acc[14] = fmaf(w, k3.z, acc[14]); acc[15] = fmaf(w, k3.w, acc[15]);
        }
        float4* ob = (float4*)(outp + ((size_t)b * CLASSES + cls) * T_DIM + t0);
        ob[0] = make_float4(acc[0], acc[1], acc[2], acc[3]);
        ob[1] = make_float4(acc[4], acc[5], acc[6], acc[7]);
        ob[2] = make_float4(acc[8], acc[9], acc[10], acc[11]);
        ob[3] = make_float4(acc[12], acc[13], acc[14], acc[15]);
    }
}

extern "C" void kernel_launch(void* const* d_in, const int* in_sizes, int n_in,
                              void* d_out, int out_size, void* d_ws, size_t ws_size,
                              hipStream_t stream) {
    const float* x   = (const float*)d_in[0];
    const float* h   = (const float*)d_in[1];
    const float* sw  = (const float*)d_in[2];
    const float* dw  = (const float*)d_in[3];
    const float* fw  = (const float*)d_in[4];
    const float* gw  = (const float*)d_in[5];
    const float* cfw = (const float*)d_in[6];
    const float* cgw = (const float*)d_in[7];
    const float* ow  = (const float*)d_in[8];
    const float* e1  = (const float*)d_in[9];
    const float* e2  = (const float*)d_in[10];
    float* out = (float*)d_out;

    const size_t SKIP_N = (size_t)B_DIM * RC * T_DIM;   // 2,097,152
    float* skip = (float*)d_ws;
    float* wAll = skip + SKIP_N;                        // 409,600
    float* e1T  = wAll + (size_t)NLAYERS * WPL;         // 8,192
    float* e2T  = e1T + RC * SC;                        // 65,536

    {   // 483,328 elements total -> 1888 blocks exactly
        int total = NLAYERS * WPL + RC * SC + SC * CLASSES;
        transpose_kernel<<<(total + 255) / 256, 256, 0, stream>>>(
            dw, fw, gw, cfw, cgw, ow, e1, e2, wAll, e1T, e2T);
    }

    fused_layers_kernel<<<B_DIM * NT, TILE_W, 0, stream>>>(x, h, sw, wAll, skip);

    end_kernel<<<B_DIM * (T_DIM / TCH), 256, 0, stream>>>(skip, e1T, e2T, out);
}

// Round 4
// 700.364 us; speedup vs baseline: 6.2491x; 3.2501x over previous
//
#include <hip/hip_runtime.h>
#include <cstddef>

#define T_DIM 16384
#define B_DIM 4
#define RC 32
#define DC 32
#define COND 80
#define SC 256
#define CLASSES 256
#define NLAYERS 40

#define TILE_W 128
#define TILE_OUT 64
#define HALO 64
#define TCH 16

// act row layout (bf16 units): [resb_hi 32 | resb_lo 32 | y/z 32 | h 80 | zero 16 | pad 8]
#define AS 200
#define CH_RH 0
#define CH_RL 32
#define CH_Z 64
#define CH_H 96
#define CH_ZERO 176

#define WPL2 11264          // packed bf16 weights per layer
#define G2_OFF 2048
#define G4_OFF 10240

typedef __bf16 bf16x8 __attribute__((ext_vector_type(8)));
typedef float f32x4 __attribute__((ext_vector_type(4)));

__device__ __forceinline__ unsigned f2bfbits(float f) {
    unsigned u = __float_as_uint(f);
    return (u + 0x7FFFu + ((u >> 16) & 1u)) >> 16;
}
__device__ __forceinline__ float bfbits2f(unsigned s) {
    return __uint_as_float(s << 16);
}
__device__ __forceinline__ f32x4 mfma16(bf16x8 a, bf16x8 b, f32x4 c) {
    return __builtin_amdgcn_mfma_f32_16x16x32_bf16(a, b, c, 0, 0, 0);
}

// ---- weight pack: A-operand fragment order (m=lane&15, k=(lane>>4)*8+j), bf16
__global__ __launch_bounds__(256) void pack_kernel(
    const float* __restrict__ dw, const float* __restrict__ fw,
    const float* __restrict__ gw, const float* __restrict__ cfw,
    const float* __restrict__ cgw, const float* __restrict__ ow,
    const float* __restrict__ e1, const float* __restrict__ e2,
    unsigned short* __restrict__ wpk, float* __restrict__ e1T,
    float* __restrict__ e2T)
{
    int idx = blockIdx.x * 256 + threadIdx.x;      // 524,288 total
    if (idx < NLAYERS * WPL2) {
        int l = idx / WPL2, o = idx % WPL2;
        float v;
        if (o < G2_OFF) {                          // conv: tile = mt*2+ks
            int t = o >> 9, li = o & 511;
            int mt = t >> 1, ks = t & 1;
            int lane = li >> 3, j = li & 7;
            int m = lane & 15, q = lane >> 4;
            int d = mt * 16 + m, r = q * 8 + j;
            v = dw[((l * 32 + d) * 32 + r) * 2 + ks];
        } else if (o < G4_OFF) {                   // gated+cond: tile = mt*4+kt
            int o2 = o - G2_OFF;
            int t = o2 >> 9, li = o2 & 511;
            int mt = t >> 2, kt = t & 3;
            int lane = li >> 3, j = li & 7;
            int m = lane & 15, q = lane >> 4;
            int row = mt * 16 + m;                 // 0..31 = f, 32..63 = g
            int kk = kt * 32 + q * 8 + j;          // 0..127: y(32) h(80) zero(16)
            int d = row & 31;
            if (kk < 32)       v = (row < 32 ? fw : gw)[(l * 32 + d) * 32 + kk];
            else if (kk < 112) v = (row < 32 ? cfw : cgw)[(l * 32 + d) * 80 + (kk - 32)];
            else               v = 0.f;
        } else {                                   // out 1x1: tile = mt
            int o3 = o - G4_OFF;
            int mt = o3 >> 9, li = o3 & 511;
            int lane = li >> 3, j = li & 7;
            int m = lane & 15, q = lane >> 4;
            int r = mt * 16 + m, d = q * 8 + j;
            v = ow[(l * 32 + r) * 32 + d];
        }
        wpk[idx] = (unsigned short)f2bfbits(v);
    } else if (idx < NLAYERS * WPL2 + RC * SC) {
        int t = idx - NLAYERS * WPL2;              // e1T[c][s] <- e1[s][c]
        int c = t >> 8, s = t & 255;
        e1T[t] = e1[s * RC + c];
    } else {
        int t = idx - NLAYERS * WPL2 - RC * SC;    // e2T[s][cls] <- e2[cls][s]
        if (t < SC * CLASSES) {
            int s = t >> 8, cls = t & 255;
            e2T[t] = e2[cls * SC + s];
        }
    }
}

// ---- all 40 layers, MFMA. Residual fp32 in regs; LDS holds bf16 activations.
__global__ __launch_bounds__(256, 3) void fused_mfma_kernel(
    const float* __restrict__ x, const float* __restrict__ h,
    const float* __restrict__ sw, const unsigned short* __restrict__ wpk,
    float* __restrict__ skip_out)
{
    __shared__ unsigned short act[TILE_W * AS];    // 51,200 B

    const int tid  = threadIdx.x;
    const int lane = tid & 63;
    const int wave = tid >> 6;
    const int quad = lane >> 4;
    const int l16  = lane & 15;
    const int b    = blockIdx.x >> 8;
    const int tile = blockIdx.x & 255;
    const int tbase = tile * TILE_OUT - HALO;

    // stage h as bf16 + zero the K-pad region
    {
        const int col = tid & 127;
        const int half = tid >> 7;
        const int gtc = max(tbase + col, 0);
        const float* hp = h + (size_t)b * COND * T_DIM + gtc;
        for (int j = half; j < COND; j += 2)
            act[col * AS + CH_H + j] = (unsigned short)f2bfbits(hp[(size_t)j * T_DIM]);
        *(uint4*)(act + col * AS + CH_ZERO + half * 8) = make_uint4(0u, 0u, 0u, 0u);
    }

    // residual registers: lane owns (ch = mt*16+quad*4+r, col = wave*32+nt*16+l16)
    const float msk = (tile > 0 || wave >= 2) ? 1.f : 0.f;
    const f32x4 zero4 = {0.f, 0.f, 0.f, 0.f};
    float xv[2];
    float swr[2][4];
    f32x4 res[2][2];

#pragma unroll
    for (int nt = 0; nt < 2; nt++) {
        int gt = tbase + wave * 32 + nt * 16 + l16;
        xv[nt] = (gt >= 0) ? x[(size_t)b * T_DIM + gt] : 0.f;
    }
#pragma unroll
    for (int mt = 0; mt < 2; mt++)
#pragma unroll
        for (int r = 0; r < 4; r++)
            swr[mt][r] = sw[mt * 16 + quad * 4 + r];
#pragma unroll
    for (int mt = 0; mt < 2; mt++)
#pragma unroll
        for (int nt = 0; nt < 2; nt++) {
#pragma unroll
            for (int r = 0; r < 4; r++) res[mt][nt][r] = swr[mt][r] * xv[nt];
            const int c = wave * 32 + nt * 16 + l16;
            const int ch0 = mt * 16 + quad * 4;
            unsigned hb[4], lb[4];
#pragma unroll
            for (int r = 0; r < 4; r++) {
                hb[r] = f2bfbits(res[mt][nt][r]);
                lb[r] = f2bfbits(res[mt][nt][r] - bfbits2f(hb[r]));
            }
            *(uint2*)(act + c * AS + CH_RH + ch0) =
                make_uint2(hb[0] | (hb[1] << 16), hb[2] | (hb[3] << 16));
            *(uint2*)(act + c * AS + CH_RL + ch0) =
                make_uint2(lb[0] | (lb[1] << 16), lb[2] | (lb[3] << 16));
        }
    __syncthreads();

    const unsigned short* wl = wpk;
    for (int l = 0; l < NLAYERS; l++, wl += WPL2) {
        // conv B-frags: read resb (prv needs col-1 -> cross-wave; read BEFORE barrier)
        bf16x8 bc[2][2][2];   // [ks: prv/cur][part: hi/lo][nt]
#pragma unroll
        for (int nt = 0; nt < 2; nt++) {
            const int c = wave * 32 + nt * 16 + l16;
            const int cp = max(c - 1, 0);
#pragma unroll
            for (int part = 0; part < 2; part++) {
                bc[0][part][nt] = *(const bf16x8*)(act + cp * AS + part * 32 + quad * 8);
                bc[1][part][nt] = *(const bf16x8*)(act + c  * AS + part * 32 + quad * 8);
            }
        }
        __syncthreads();   // A: all conv reads done before this layer's resb writes

        // GEMM1: y[32] = Wdil . [prv;cur]  (hi+lo, same A reused)
        f32x4 acc1[2][2];
#pragma unroll
        for (int mt = 0; mt < 2; mt++)
#pragma unroll
            for (int nt = 0; nt < 2; nt++) acc1[mt][nt] = zero4;
#pragma unroll
        for (int ks = 0; ks < 2; ks++)
#pragma unroll
            for (int mt = 0; mt < 2; mt++) {
                bf16x8 a = *(const bf16x8*)(wl + (mt * 2 + ks) * 512 + lane * 8);
#pragma unroll
                for (int part = 0; part < 2; part++)
#pragma unroll
                    for (int nt = 0; nt < 2; nt++)
                        acc1[mt][nt] = mfma16(a, bc[ks][part][nt], acc1[mt][nt]);
            }

        // pack y -> CH_Z
#pragma unroll
        for (int mt = 0; mt < 2; mt++)
#pragma unroll
            for (int nt = 0; nt < 2; nt++) {
                const int c = wave * 32 + nt * 16 + l16;
                unsigned p0 = f2bfbits(acc1[mt][nt][0]) | (f2bfbits(acc1[mt][nt][1]) << 16);
                unsigned p1 = f2bfbits(acc1[mt][nt][2]) | (f2bfbits(acc1[mt][nt][3]) << 16);
                *(uint2*)(act + c * AS + CH_Z + mt * 16 + quad * 4) = make_uint2(p0, p1);
            }

        // GEMM2: [f;g] = W . [y | h | 0]  (M=64, K=128)
        f32x4 acc2[4][2];
#pragma unroll
        for (int mt = 0; mt < 4; mt++)
#pragma unroll
            for (int nt = 0; nt < 2; nt++) acc2[mt][nt] = zero4;
#pragma unroll
        for (int kt = 0; kt < 4; kt++) {
            bf16x8 bb[2];
#pragma unroll
            for (int nt = 0; nt < 2; nt++) {
                const int c = wave * 32 + nt * 16 + l16;
                bb[nt] = *(const bf16x8*)(act + c * AS + CH_Z + kt * 32 + quad * 8);
            }
#pragma unroll
            for (int mt = 0; mt < 4; mt++) {
                bf16x8 a = *(const bf16x8*)(wl + G2_OFF + (mt * 4 + kt) * 512 + lane * 8);
#pragma unroll
                for (int nt = 0; nt < 2; nt++)
                    acc2[mt][nt] = mfma16(a, bb[nt], acc2[mt][nt]);
            }
        }

        // glue: z = tanh(f) * sigmoid(g); pack z -> CH_Z (overwrites y, same wave)
#pragma unroll
        for (int mt = 0; mt < 2; mt++)
#pragma unroll
            for (int nt = 0; nt < 2; nt++) {
                const int c = wave * 32 + nt * 16 + l16;
                unsigned zp[4];
#pragma unroll
                for (int r = 0; r < 4; r++) {
                    float fa = acc2[mt][nt][r];
                    float ga = acc2[mt + 2][nt][r];
                    float xc = fminf(fmaxf(fa, -15.f), 15.f);
                    float ev = __expf(2.f * xc);
                    float th = 1.f - 2.f / (ev + 1.f);
                    float sg = 1.f / (1.f + __expf(-ga));
                    zp[r] = f2bfbits(th * sg);
                }
                *(uint2*)(act + c * AS + CH_Z + mt * 16 + quad * 4) =
                    make_uint2(zp[0] | (zp[1] << 16), zp[2] | (zp[3] << 16));
            }

        // GEMM4: out[32] = Wout . z
        f32x4 acc4[2][2];
#pragma unroll
        for (int mt = 0; mt < 2; mt++)
#pragma unroll
            for (int nt = 0; nt < 2; nt++) acc4[mt][nt] = zero4;
        bf16x8 bz[2];
#pragma unroll
        for (int nt = 0; nt < 2; nt++) {
            const int c = wave * 32 + nt * 16 + l16;
            bz[nt] = *(const bf16x8*)(act + c * AS + CH_Z + quad * 8);
        }
#pragma unroll
        for (int mt = 0; mt < 2; mt++) {
            bf16x8 a = *(const bf16x8*)(wl + G4_OFF + mt * 512 + lane * 8);
#pragma unroll
            for (int nt = 0; nt < 2; nt++)
                acc4[mt][nt] = mfma16(a, bz[nt], acc4[mt][nt]);
        }

        // residual update (fp32 regs) + resb hi/lo write
#pragma unroll
        for (int mt = 0; mt < 2; mt++)
#pragma unroll
            for (int nt = 0; nt < 2; nt++) {
                const int c = wave * 32 + nt * 16 + l16;
                const int ch0 = mt * 16 + quad * 4;
                f32x4 nr = (res[mt][nt] + acc4[mt][nt]) * msk;
                res[mt][nt] = nr;
                unsigned hb[4], lb[4];
#pragma unroll
                for (int r = 0; r < 4; r++) {
                    hb[r] = f2bfbits(nr[r]);
                    lb[r] = f2bfbits(nr[r] - bfbits2f(hb[r]));
                }
                *(uint2*)(act + c * AS + CH_RH + ch0) =
                    make_uint2(hb[0] | (hb[1] << 16), hb[2] | (hb[3] << 16));
                *(uint2*)(act + c * AS + CH_RL + ch0) =
                    make_uint2(lb[0] | (lb[1] << 16), lb[2] | (lb[3] << 16));
            }
        __syncthreads();   // B: resb writes visible before next layer's reads
    }

    // epilogue: skip = res_final - res_0 ; output cols 64..127 = waves 2,3
    if (wave >= 2) {
#pragma unroll
        for (int mt = 0; mt < 2; mt++)
#pragma unroll
            for (int nt = 0; nt < 2; nt++) {
                const int c = wave * 32 + nt * 16 + l16;
                const int gt = tbase + c;
#pragma unroll
                for (int r = 0; r < 4; r++) {
                    const int ch = mt * 16 + quad * 4 + r;
                    skip_out[((size_t)b * RC + ch) * T_DIM + gt] =
                        res[mt][nt][r] - swr[mt][r] * xv[nt];
                }
            }
    }
}

// ---- end: relu->e1->relu->e2 (fp32, coalesced transposed weights)
__global__ __launch_bounds__(256) void end_kernel(
    const float* __restrict__ skip,   // [B,32,T]
    const float* __restrict__ e1T,    // [32][256]
    const float* __restrict__ e2T,    // [256][256]
    float* __restrict__ outp)         // [B][256][T]
{
    __shared__ float s_sk[RC][TCH];
    __shared__ float s_e[SC][TCH];

    const int blk = blockIdx.x;                 // 4096
    const int b = blk >> 10;
    const int t0 = (blk & 1023) * TCH;
    const int tid = threadIdx.x;

    if (tid < 128) {
        int c = tid >> 2, q = tid & 3;
        const float* sp = skip + ((size_t)b * RC + c) * T_DIM + t0 + q * 4;
        float4 v = *(const float4*)sp;
        v.x = fmaxf(v.x, 0.f); v.y = fmaxf(v.y, 0.f);
        v.z = fmaxf(v.z, 0.f); v.w = fmaxf(v.w, 0.f);
        *(float4*)&s_sk[c][q * 4] = v;
    }
    __syncthreads();

    float acc[TCH];
#pragma unroll
    for (int p = 0; p < TCH; p++) acc[p] = 0.f;
    {
        const int s = tid;
#pragma unroll 2
        for (int c = 0; c < RC; c++) {
            float w = e1T[c * SC + s];
            const float4* row = (const float4*)&s_sk[c][0];
            float4 k0 = row[0], k1 = row[1], k2 = row[2], k3 = row[3];
            acc[0]  = fmaf(w, k0.x, acc[0]);  acc[1]  = fmaf(w, k0.y, acc[1]);
            acc[2]  = fmaf(w, k0.z, acc[2]);  acc[3]  = fmaf(w, k0.w, acc[3]);
            acc[4]  = fmaf(w, k1.x, acc[4]);  acc[5]  = fmaf(w, k1.y, acc[5]);
            acc[6]  = fmaf(w, k1.z, acc[6]);  acc[7]  = fmaf(w, k1.w, acc[7]);
            acc[8]  = fmaf(w, k2.x, acc[8]);  acc[9]  = fmaf(w, k2.y, acc[9]);
            acc[10] = fmaf(w, k2.z, acc[10]); acc[11] = fmaf(w, k2.w, acc[11]);
            acc[12] = fmaf(w, k3.x, acc[12]); acc[13] = fmaf(w, k3.y, acc[13]);
            acc[14] = fmaf(w, k3.z, acc[14]); acc[15] = fmaf(w, k3.w, acc[15]);
        }
        float4* er = (float4*)&s_e[tid][0];
        er[0] = make_float4(fmaxf(acc[0],0.f),  fmaxf(acc[1],0.f),
                            fmaxf(acc[2],0.f),  fmaxf(acc[3],0.f));
        er[1] = make_float4(fmaxf(acc[4],0.f),  fmaxf(acc[5],0.f),
                            fmaxf(acc[6],0.f),  fmaxf(acc[7],0.f));
        er[2] = make_float4(fmaxf(acc[8],0.f),  fmaxf(acc[9],0.f),
                            fmaxf(acc[10],0.f), fmaxf(acc[11],0.f));
        er[3] = make_float4(fmaxf(acc[12],0.f), fmaxf(acc[13],0.f),
                            fmaxf(acc[14],0.f), fmaxf(acc[15],0.f));
    }
    __syncthreads();

#pragma unroll
    for (int p = 0; p < TCH; p++) acc[p] = 0.f;
    {
        const int cls = tid;
#pragma unroll 2
        for (int s2 = 0; s2 < SC; s2++) {
            float w = e2T[s2 * CLASSES + cls];
            const float4* row = (const float4*)&s_e[s2][0];
            float4 k0 = row[0], k1 = row[1], k2 = row[2], k3 = row[3];
            acc[0]  = fmaf(w, k0.x, acc[0]);  acc[1]  = fmaf(w, k0.y, acc[1]);
            acc[2]  = fmaf(w, k0.z, acc[2]);  acc[3]  = fmaf(w, k0.w, acc[3]);
            acc[4]  = fmaf(w, k1.x, acc[4]);  acc[5]  = fmaf(w, k1.y, acc[5]);
            acc[6]  = fmaf(w, k1.z, acc[6]);  acc[7]  = fmaf(w, k1.w, acc[7]);
            acc[8]  = fmaf(w, k2.x, acc[8]);  acc[9]  = fmaf(w, k2.y, acc[9]);
            acc[10] = fmaf(w, k2.z, acc[10]); acc[11] = fmaf(w, k2.w, acc[11]);
            acc[12] = fmaf(w, k3.x, acc[12]); acc[13] = fmaf(w, k3.y, acc[13]);
            acc[14] = fmaf(w, k3.z, acc[14]); acc[15] = fmaf(w, k3.w, acc[15]);
        }
        float4* ob = (float4*)(outp + ((size_t)b * CLASSES + cls) * T_DIM + t0);
        ob[0] = make_float4(acc[0], acc[1], acc[2], acc[3]);
        ob[1] = make_float4(acc[4], acc[5], acc[6], acc[7]);
        ob[2] = make_float4(acc[8], acc[9], acc[10], acc[11]);
        ob[3] = make_float4(acc[12], acc[13], acc[14], acc[15]);
    }
}

extern "C" void kernel_launch(void* const* d_in, const int* in_sizes, int n_in,
                              void* d_out, int out_size, void* d_ws, size_t ws_size,
                              hipStream_t stream) {
    const float* x   = (const float*)d_in[0];
    const float* h   = (const float*)d_in[1];
    const float* sw  = (const float*)d_in[2];
    const float* dw  = (const float*)d_in[3];
    const float* fw  = (const float*)d_in[4];
    const float* gw  = (const float*)d_in[5];
    const float* cfw = (const float*)d_in[6];
    const float* cgw = (const float*)d_in[7];
    const float* ow  = (const float*)d_in[8];
    const float* e1  = (const float*)d_in[9];
    const float* e2  = (const float*)d_in[10];
    float* out = (float*)d_out;

    const size_t SKIP_N = (size_t)B_DIM * RC * T_DIM;   // 2,097,152 floats
    float* skip = (float*)d_ws;
    float* e1T  = skip + SKIP_N;
    float* e2T  = e1T + RC * SC;
    unsigned short* wpk = (unsigned short*)(e2T + (size_t)SC * CLASSES);

    {   // 450,560 + 8,192 + 65,536 = 524,288 -> 2048 blocks
        pack_kernel<<<2048, 256, 0, stream>>>(dw, fw, gw, cfw, cgw, ow, e1, e2,
                                              wpk, e1T, e2T);
    }

    fused_mfma_kernel<<<B_DIM * 256, 256, 0, stream>>>(x, h, sw, wpk, skip);

    end_kernel<<<B_DIM * (T_DIM / TCH), 256, 0, stream>>>(skip, e1T, e2T, out);
}

// Round 5
// 281.615 us; speedup vs baseline: 15.5413x; 2.4870x over previous
//
#include <hip/hip_runtime.h>
#include <hip/hip_bf16.h>
#include <cstddef>

#define T_DIM 16384
#define B_DIM 4
#define RC 32
#define DC 32
#define COND 80
#define SC 256
#define CLASSES 256
#define NLAYERS 40

#define TILE_W 128
#define HALO 40            // exact receptive field of 40 K=2 causal layers
#define TILE_OUT 88
#define NT 187             // ceil(16384/88)

// act row layout (bf16 units): [resb_hi 32 | resb_lo 32 | y/z 32 | h 80]
#define AS 176
#define CH_RH 0
#define CH_RL 32
#define CH_Z 64
#define CH_H 96

#define WPL2 11264          // packed bf16 weights per layer
#define G2_OFF 2048
#define G4_OFF 10240

typedef __bf16 bf16x8 __attribute__((ext_vector_type(8)));
typedef float f32x4 __attribute__((ext_vector_type(4)));

__device__ __forceinline__ unsigned f2bfbits(float f) {
    unsigned u = __float_as_uint(f);
    return (u + 0x7FFFu + ((u >> 16) & 1u)) >> 16;
}
// packed RNE f32x2 -> bf16x2 (lowers to v_cvt_pk_bf16_f32 where available)
__device__ __forceinline__ unsigned pk2(float a, float b) {
    __hip_bfloat162 v = __float22bfloat162_rn(make_float2(a, b));
    union { __hip_bfloat162 h; unsigned u; } cv;
    cv.h = v;
    return cv.u;
}
__device__ __forceinline__ f32x4 mfma16(bf16x8 a, bf16x8 b, f32x4 c) {
    return __builtin_amdgcn_mfma_f32_16x16x32_bf16(a, b, c, 0, 0, 0);
}

// ---- weight pack: A-operand fragment order (m=lane&15, k=(lane>>4)*8+j), bf16
__global__ __launch_bounds__(256) void pack_kernel(
    const float* __restrict__ dw, const float* __restrict__ fw,
    const float* __restrict__ gw, const float* __restrict__ cfw,
    const float* __restrict__ cgw, const float* __restrict__ ow,
    const float* __restrict__ e1, const float* __restrict__ e2,
    unsigned short* __restrict__ wpk, unsigned short* __restrict__ e1pk,
    unsigned short* __restrict__ e2pk)
{
    int idx = blockIdx.x * 256 + threadIdx.x;      // 524,288 total exactly
    if (idx < NLAYERS * WPL2) {
        int l = idx / WPL2, o = idx % WPL2;
        float v;
        if (o < G2_OFF) {                          // conv: tile = mt*2+ks
            int t = o >> 9, li = o & 511;
            int mt = t >> 1, ks = t & 1;
            int lane = li >> 3, j = li & 7;
            int m = lane & 15, q = lane >> 4;
            int d = mt * 16 + m, r = q * 8 + j;
            v = dw[((l * 32 + d) * 32 + r) * 2 + ks];
        } else if (o < G4_OFF) {                   // gated+cond: tile = mt*4+kt
            int o2 = o - G2_OFF;
            int t = o2 >> 9, li = o2 & 511;
            int mt = t >> 2, kt = t & 3;
            int lane = li >> 3, j = li & 7;
            int m = lane & 15, q = lane >> 4;
            int row = mt * 16 + m;                 // 0..31 = f, 32..63 = g
            int kk = kt * 32 + q * 8 + j;          // 0..127: y(32) h(80) zero(16)
            int d = row & 31;
            if (kk < 32)       v = (row < 32 ? fw : gw)[(l * 32 + d) * 32 + kk];
            else if (kk < 112) v = (row < 32 ? cfw : cgw)[(l * 32 + d) * 80 + (kk - 32)];
            else               v = 0.f;
        } else {                                   // out 1x1: tile = mt
            int o3 = o - G4_OFF;
            int mt = o3 >> 9, li = o3 & 511;
            int lane = li >> 3, j = li & 7;
            int m = lane & 15, q = lane >> 4;
            int r = mt * 16 + m, d = q * 8 + j;
            v = ow[(l * 32 + r) * 32 + d];
        }
        wpk[idx] = (unsigned short)f2bfbits(v);
    } else if (idx < NLAYERS * WPL2 + 16 * 512) {  // e1pk: 16 m-tiles, K=32
        int o = idx - NLAYERS * WPL2;
        int mt = o >> 9, li = o & 511;
        int lane = li >> 3, j = li & 7;
        int m = lane & 15, q = lane >> 4;
        int s = mt * 16 + m, c = q * 8 + j;
        e1pk[o] = (unsigned short)f2bfbits(e1[s * RC + c]);
    } else {                                       // e2pk: (mt*8+kf) tiles
        int o = idx - NLAYERS * WPL2 - 16 * 512;   // < 65536 exactly
        int t = o >> 9, li = o & 511;
        int mt = t >> 3, kf = t & 7;
        int lane = li >> 3, j = li & 7;
        int m = lane & 15, q = lane >> 4;
        int cls = mt * 16 + m, k = kf * 32 + q * 8 + j;
        e2pk[o] = (unsigned short)f2bfbits(e2[cls * SC + k]);
    }
}

// ---- all 40 layers, MFMA. Residual fp32 in regs; LDS holds bf16 activations.
__global__ __launch_bounds__(256, 3) void fused_mfma_kernel(
    const float* __restrict__ x, const float* __restrict__ h,
    const float* __restrict__ sw, const unsigned short* __restrict__ wpk,
    float* __restrict__ skip_out)
{
    __shared__ unsigned short act[TILE_W * AS];    // 45,056 B -> 3 blocks/CU

    const int tid  = threadIdx.x;
    const int lane = tid & 63;
    const int wave = tid >> 6;
    const int quad = lane >> 4;
    const int l16  = lane & 15;
    const int b    = blockIdx.x / NT;
    const int tile = blockIdx.x % NT;
    const int tbase = tile * TILE_OUT - HALO;

    // stage h as bf16 (clamped both edges)
    {
        const int col = tid & 127;
        const int half = tid >> 7;
        const int gtc = min(max(tbase + col, 0), T_DIM - 1);
        const float* hp = h + (size_t)b * COND * T_DIM + gtc;
        for (int j = half; j < COND; j += 2)
            act[col * AS + CH_H + j] = (unsigned short)f2bfbits(hp[(size_t)j * T_DIM]);
    }

    // residual registers: lane owns (ch = mt*16+quad*4+r, col = wave*32+nt*16+l16)
    const f32x4 zero4 = {0.f, 0.f, 0.f, 0.f};
    bf16x8 zfrag;
    *(uint4*)&zfrag = make_uint4(0u, 0u, 0u, 0u);
    float xv[2], mskv[2];
    float swr[2][4];
    f32x4 res[2][2];

#pragma unroll
    for (int nt = 0; nt < 2; nt++) {
        int gt = tbase + wave * 32 + nt * 16 + l16;
        int gx = min(max(gt, 0), T_DIM - 1);
        float v = x[(size_t)b * T_DIM + gx];
        mskv[nt] = (gt >= 0) ? 1.f : 0.f;
        xv[nt] = v * mskv[nt];
    }
#pragma unroll
    for (int mt = 0; mt < 2; mt++)
#pragma unroll
        for (int r = 0; r < 4; r++)
            swr[mt][r] = sw[mt * 16 + quad * 4 + r];
#pragma unroll
    for (int mt = 0; mt < 2; mt++)
#pragma unroll
        for (int nt = 0; nt < 2; nt++) {
#pragma unroll
            for (int r = 0; r < 4; r++) res[mt][nt][r] = swr[mt][r] * xv[nt];
            const int c = wave * 32 + nt * 16 + l16;
            const int ch0 = mt * 16 + quad * 4;
            unsigned h0 = pk2(res[mt][nt][0], res[mt][nt][1]);
            unsigned h1 = pk2(res[mt][nt][2], res[mt][nt][3]);
            float f0 = __uint_as_float(h0 << 16);
            float f1 = __uint_as_float(h0 & 0xFFFF0000u);
            float f2 = __uint_as_float(h1 << 16);
            float f3 = __uint_as_float(h1 & 0xFFFF0000u);
            unsigned l0 = pk2(res[mt][nt][0] - f0, res[mt][nt][1] - f1);
            unsigned l1 = pk2(res[mt][nt][2] - f2, res[mt][nt][3] - f3);
            *(uint2*)(act + c * AS + CH_RH + ch0) = make_uint2(h0, h1);
            *(uint2*)(act + c * AS + CH_RL + ch0) = make_uint2(l0, l1);
        }
    __syncthreads();

    const unsigned short* wl = wpk;
    for (int l = 0; l < NLAYERS; l++, wl += WPL2) {
        // conv B-frags (prv needs col-1 -> cross-wave; read BEFORE barrier)
        bf16x8 bc[2][2][2];   // [ks: prv/cur][part: hi/lo][nt]
#pragma unroll
        for (int nt = 0; nt < 2; nt++) {
            const int c = wave * 32 + nt * 16 + l16;
            const int cp = max(c - 1, 0);
#pragma unroll
            for (int part = 0; part < 2; part++) {
                bc[0][part][nt] = *(const bf16x8*)(act + cp * AS + part * 32 + quad * 8);
                bc[1][part][nt] = *(const bf16x8*)(act + c  * AS + part * 32 + quad * 8);
            }
        }
        __syncthreads();   // A: conv reads done before this layer's resb writes

        // GEMM1: y[32] = Wdil . [prv;cur]  (hi+lo, same A reused)
        f32x4 acc1[2][2];
#pragma unroll
        for (int mt = 0; mt < 2; mt++)
#pragma unroll
            for (int nt = 0; nt < 2; nt++) acc1[mt][nt] = zero4;
#pragma unroll
        for (int ks = 0; ks < 2; ks++)
#pragma unroll
            for (int mt = 0; mt < 2; mt++) {
                bf16x8 a = *(const bf16x8*)(wl + (mt * 2 + ks) * 512 + lane * 8);
#pragma unroll
                for (int part = 0; part < 2; part++)
#pragma unroll
                    for (int nt = 0; nt < 2; nt++)
                        acc1[mt][nt] = mfma16(a, bc[ks][part][nt], acc1[mt][nt]);
            }

        // pack y -> CH_Z
#pragma unroll
        for (int mt = 0; mt < 2; mt++)
#pragma unroll
            for (int nt = 0; nt < 2; nt++) {
                const int c = wave * 32 + nt * 16 + l16;
                unsigned p0 = pk2(acc1[mt][nt][0], acc1[mt][nt][1]);
                unsigned p1 = pk2(acc1[mt][nt][2], acc1[mt][nt][3]);
                *(uint2*)(act + c * AS + CH_Z + mt * 16 + quad * 4) = make_uint2(p0, p1);
            }

        // GEMM2: [f;g] = W . [y | h]  (M=64, K=128, K-tail zeros in registers)
        f32x4 acc2[4][2];
#pragma unroll
        for (int mt = 0; mt < 4; mt++)
#pragma unroll
            for (int nt = 0; nt < 2; nt++) acc2[mt][nt] = zero4;
#pragma unroll
        for (int kt = 0; kt < 4; kt++) {
            bf16x8 bb[2];
#pragma unroll
            for (int nt = 0; nt < 2; nt++) {
                const int c = wave * 32 + nt * 16 + l16;
                if (kt < 3) {
                    bb[nt] = *(const bf16x8*)(act + c * AS + CH_Z + kt * 32 + quad * 8);
                } else {
                    bf16x8 t = *(const bf16x8*)(act + c * AS + CH_Z + 96 + (quad & 1) * 8);
                    bb[nt] = (quad < 2) ? t : zfrag;
                }
            }
#pragma unroll
            for (int mt = 0; mt < 4; mt++) {
                bf16x8 a = *(const bf16x8*)(wl + G2_OFF + (mt * 4 + kt) * 512 + lane * 8);
#pragma unroll
                for (int nt = 0; nt < 2; nt++)
                    acc2[mt][nt] = mfma16(a, bb[nt], acc2[mt][nt]);
            }
        }

        // glue: z = tanh(f)*sigmoid(g)  (inf-safe, v_rcp) ; pack z -> CH_Z
#pragma unroll
        for (int mt = 0; mt < 2; mt++)
#pragma unroll
            for (int nt = 0; nt < 2; nt++) {
                const int c = wave * 32 + nt * 16 + l16;
                float z[4];
#pragma unroll
                for (int r = 0; r < 4; r++) {
                    float fa = acc2[mt][nt][r];
                    float ga = acc2[mt + 2][nt][r];
                    float ev = __expf(2.f * fa);
                    float th = 1.f - 2.f * __builtin_amdgcn_rcpf(ev + 1.f);
                    float sg = __builtin_amdgcn_rcpf(1.f + __expf(-ga));
                    z[r] = th * sg;
                }
                *(uint2*)(act + c * AS + CH_Z + mt * 16 + quad * 4) =
                    make_uint2(pk2(z[0], z[1]), pk2(z[2], z[3]));
            }

        // GEMM4: out[32] = Wout . z
        f32x4 acc4[2][2];
#pragma unroll
        for (int mt = 0; mt < 2; mt++)
#pragma unroll
            for (int nt = 0; nt < 2; nt++) acc4[mt][nt] = zero4;
        bf16x8 bz[2];
#pragma unroll
        for (int nt = 0; nt < 2; nt++) {
            const int c = wave * 32 + nt * 16 + l16;
            bz[nt] = *(const bf16x8*)(act + c * AS + CH_Z + quad * 8);
        }
#pragma unroll
        for (int mt = 0; mt < 2; mt++) {
            bf16x8 a = *(const bf16x8*)(wl + G4_OFF + mt * 512 + lane * 8);
#pragma unroll
            for (int nt = 0; nt < 2; nt++)
                acc4[mt][nt] = mfma16(a, bz[nt], acc4[mt][nt]);
        }

        // residual update (fp32 regs) + resb hi/lo write
#pragma unroll
        for (int mt = 0; mt < 2; mt++)
#pragma unroll
            for (int nt = 0; nt < 2; nt++) {
                const int c = wave * 32 + nt * 16 + l16;
                const int ch0 = mt * 16 + quad * 4;
                f32x4 nr = (res[mt][nt] + acc4[mt][nt]) * mskv[nt];
                res[mt][nt] = nr;
                unsigned h0 = pk2(nr[0], nr[1]);
                unsigned h1 = pk2(nr[2], nr[3]);
                float f0 = __uint_as_float(h0 << 16);
                float f1 = __uint_as_float(h0 & 0xFFFF0000u);
                float f2 = __uint_as_float(h1 << 16);
                float f3 = __uint_as_float(h1 & 0xFFFF0000u);
                unsigned l0 = pk2(nr[0] - f0, nr[1] - f1);
                unsigned l1 = pk2(nr[2] - f2, nr[3] - f3);
                *(uint2*)(act + c * AS + CH_RH + ch0) = make_uint2(h0, h1);
                *(uint2*)(act + c * AS + CH_RL + ch0) = make_uint2(l0, l1);
            }
        __syncthreads();   // B: resb writes visible before next layer's reads
    }

    // epilogue: skip = res_final - res_0 (cols >= HALO, in range)
#pragma unroll
    for (int mt = 0; mt < 2; mt++)
#pragma unroll
        for (int nt = 0; nt < 2; nt++) {
            const int c = wave * 32 + nt * 16 + l16;
            const int gt = tbase + c;
            if (c >= HALO && gt < T_DIM) {
#pragma unroll
                for (int r = 0; r < 4; r++) {
                    const int ch = mt * 16 + quad * 4 + r;
                    skip_out[((size_t)b * RC + ch) * T_DIM + gt] =
                        res[mt][nt][r] - swr[mt][r] * xv[nt];
                }
            }
        }
}

// ---- end: relu->e1->relu->e2 with MFMA (bf16). Block = 64 cols, M=256.
__global__ __launch_bounds__(256) void end_kernel(
    const float* __restrict__ skip,          // [B,32,T]
    const unsigned short* __restrict__ e1pk, // A-frags [16 mt][512]
    const unsigned short* __restrict__ e2pk, // A-frags [16 mt * 8 kf][512]
    float* __restrict__ outp)                // [B][256][T]
{
    __shared__ unsigned short sk_s[64 * 40];    // [col][ch], pad 32->40
    __shared__ unsigned short e_s[64 * 264];    // [col][s], pad 256->264

    const int tid  = threadIdx.x;
    const int lane = tid & 63;
    const int wave = tid >> 6;
    const int quad = lane >> 4;
    const int l16  = lane & 15;
    const int b  = blockIdx.x >> 8;
    const int t0 = (blockIdx.x & 255) * 64;

    // stage relu(skip) -> bf16 [col][ch]
    {
        const int col = tid & 63;
        const int cg = tid >> 6;           // 4 channel groups of 8
        const float* sp = skip + ((size_t)b * RC + cg * 8) * T_DIM + t0 + col;
        float v[8];
#pragma unroll
        for (int k = 0; k < 8; k++)
            v[k] = fmaxf(sp[(size_t)k * T_DIM], 0.f);
        unsigned u0 = pk2(v[0], v[1]), u1 = pk2(v[2], v[3]);
        unsigned u2 = pk2(v[4], v[5]), u3 = pk2(v[6], v[7]);
        *(uint2*)(sk_s + col * 40 + cg * 8)     = make_uint2(u0, u1);
        *(uint2*)(sk_s + col * 40 + cg * 8 + 4) = make_uint2(u2, u3);
    }
    __syncthreads();

    // phase 1: e[256 s][64 col] = relu(e1 . sk) ; wave handles 4 m-tiles
    {
        bf16x8 bb[4];
#pragma unroll
        for (int ntl = 0; ntl < 4; ntl++)
            bb[ntl] = *(const bf16x8*)(sk_s + (ntl * 16 + l16) * 40 + quad * 8);
#pragma unroll
        for (int mtl = 0; mtl < 4; mtl++) {
            const int mt = wave * 4 + mtl;
            bf16x8 a = *(const bf16x8*)(e1pk + mt * 512 + lane * 8);
            f32x4 acc[4];
#pragma unroll
            for (int ntl = 0; ntl < 4; ntl++) {
                acc[ntl] = mfma16(a, bb[ntl], (f32x4){0.f, 0.f, 0.f, 0.f});
            }
#pragma unroll
            for (int ntl = 0; ntl < 4; ntl++) {
                const int col = ntl * 16 + l16;
                unsigned p0 = pk2(fmaxf(acc[ntl][0], 0.f), fmaxf(acc[ntl][1], 0.f));
                unsigned p1 = pk2(fmaxf(acc[ntl][2], 0.f), fmaxf(acc[ntl][3], 0.f));
                *(uint2*)(e_s + col * 264 + mt * 16 + quad * 4) = make_uint2(p0, p1);
            }
        }
    }
    __syncthreads();

    // phase 2: logits[256 cls][64 col] = e2 . e ; wave: 4 m-tiles x 4 n x 8 k
    {
        f32x4 acc[4][4];
#pragma unroll
        for (int mtl = 0; mtl < 4; mtl++)
#pragma unroll
            for (int ntl = 0; ntl < 4; ntl++) acc[mtl][ntl] = (f32x4){0.f, 0.f, 0.f, 0.f};

        for (int kf = 0; kf < 8; kf++) {
            bf16x8 bb[4];
#pragma unroll
            for (int ntl = 0; ntl < 4; ntl++)
                bb[ntl] = *(const bf16x8*)(e_s + (ntl * 16 + l16) * 264 + kf * 32 + quad * 8);
#pragma unroll
            for (int mtl = 0; mtl < 4; mtl++) {
                const int mt = wave * 4 + mtl;
                bf16x8 a = *(const bf16x8*)(e2pk + (mt * 8 + kf) * 512 + lane * 8);
#pragma unroll
                for (int ntl = 0; ntl < 4; ntl++)
                    acc[mtl][ntl] = mfma16(a, bb[ntl], acc[mtl][ntl]);
            }
        }

#pragma unroll
        for (int mtl = 0; mtl < 4; mtl++)
#pragma unroll
            for (int ntl = 0; ntl < 4; ntl++) {
                const int cls0 = (wave * 4 + mtl) * 16 + quad * 4;
                const int col = ntl * 16 + l16;
#pragma unroll
                for (int r = 0; r < 4; r++)
                    outp[((size_t)b * CLASSES + cls0 + r) * T_DIM + t0 + col] =
                        acc[mtl][ntl][r];
            }
    }
}

extern "C" void kernel_launch(void* const* d_in, const int* in_sizes, int n_in,
                              void* d_out, int out_size, void* d_ws, size_t ws_size,
                              hipStream_t stream) {
    const float* x   = (const float*)d_in[0];
    const float* h   = (const float*)d_in[1];
    const float* sw  = (const float*)d_in[2];
    const float* dw  = (const float*)d_in[3];
    const float* fw  = (const float*)d_in[4];
    const float* gw  = (const float*)d_in[5];
    const float* cfw = (const float*)d_in[6];
    const float* cgw = (const float*)d_in[7];
    const float* ow  = (const float*)d_in[8];
    const float* e1  = (const float*)d_in[9];
    const float* e2  = (const float*)d_in[10];
    float* out = (float*)d_out;

    const size_t SKIP_N = (size_t)B_DIM * RC * T_DIM;   // 2,097,152 floats
    float* skip = (float*)d_ws;
    unsigned short* wpk  = (unsigned short*)(skip + SKIP_N);
    unsigned short* e1pk = wpk + (size_t)NLAYERS * WPL2;
    unsigned short* e2pk = e1pk + 16 * 512;

    // 450,560 + 8,192 + 65,536 = 524,288 -> 2048 blocks exactly
    pack_kernel<<<2048, 256, 0, stream>>>(dw, fw, gw, cfw, cgw, ow, e1, e2,
                                          wpk, e1pk, e2pk);

    fused_mfma_kernel<<<B_DIM * NT, 256, 0, stream>>>(x, h, sw, wpk, skip);

    end_kernel<<<B_DIM * 256, 256, 0, stream>>>(skip, e1pk, e2pk, out);
}

// Round 6
// 268.756 us; speedup vs baseline: 16.2849x; 1.0478x over previous
//
#include <hip/hip_runtime.h>
#include <hip/hip_bf16.h>
#include <cstddef>

#define T_DIM 16384
#define B_DIM 4
#define RC 32
#define DC 32
#define COND 80
#define SC 256
#define CLASSES 256
#define NLAYERS 40

#define TILE_W 128
#define HALO 40            // exact receptive field of 40 K=2 causal layers
#define TILE_OUT 88
#define NT 187             // ceil(16384/88)

// act row layout (bf16 units): [resb 32 | y/z 32 | h 80 | zero 16 | pad 8]
// AS=168 -> 84-dword stride, gcd(21,8): lane-stride 20 mod 32 -> 2-way max (free)
#define AS 168
#define CH_RH 0
#define CH_Z 32
#define CH_H 64
#define CH_ZERO 144

#define WPL2 11264          // packed bf16 weights per layer
#define G2_OFF 2048
#define G4_OFF 10240

typedef __bf16 bf16x8 __attribute__((ext_vector_type(8)));
typedef float f32x4 __attribute__((ext_vector_type(4)));

__device__ __forceinline__ unsigned f2bfbits(float f) {
    unsigned u = __float_as_uint(f);
    return (u + 0x7FFFu + ((u >> 16) & 1u)) >> 16;
}
// packed RNE f32x2 -> bf16x2
__device__ __forceinline__ unsigned pk2(float a, float b) {
    __hip_bfloat162 v = __float22bfloat162_rn(make_float2(a, b));
    union { __hip_bfloat162 h; unsigned u; } cv;
    cv.h = v;
    return cv.u;
}
__device__ __forceinline__ f32x4 mfma16(bf16x8 a, bf16x8 b, f32x4 c) {
    return __builtin_amdgcn_mfma_f32_16x16x32_bf16(a, b, c, 0, 0, 0);
}

// ---- weight pack: A-operand fragment order (m=lane&15, k=(lane>>4)*8+j), bf16
__global__ __launch_bounds__(256) void pack_kernel(
    const float* __restrict__ dw, const float* __restrict__ fw,
    const float* __restrict__ gw, const float* __restrict__ cfw,
    const float* __restrict__ cgw, const float* __restrict__ ow,
    const float* __restrict__ e1, const float* __restrict__ e2,
    unsigned short* __restrict__ wpk, unsigned short* __restrict__ e1pk,
    unsigned short* __restrict__ e2pk)
{
    int idx = blockIdx.x * 256 + threadIdx.x;      // 524,288 total exactly
    if (idx < NLAYERS * WPL2) {
        int l = idx / WPL2, o = idx % WPL2;
        float v;
        if (o < G2_OFF) {                          // conv: tile = mt*2+ks
            int t = o >> 9, li = o & 511;
            int mt = t >> 1, ks = t & 1;
            int lane = li >> 3, j = li & 7;
            int m = lane & 15, q = lane >> 4;
            int d = mt * 16 + m, r = q * 8 + j;
            v = dw[((l * 32 + d) * 32 + r) * 2 + ks];
        } else if (o < G4_OFF) {                   // gated+cond: tile = mt*4+kt
            int o2 = o - G2_OFF;
            int t = o2 >> 9, li = o2 & 511;
            int mt = t >> 2, kt = t & 3;
            int lane = li >> 3, j = li & 7;
            int m = lane & 15, q = lane >> 4;
            int row = mt * 16 + m;                 // 0..31 = f, 32..63 = g
            int kk = kt * 32 + q * 8 + j;          // 0..127: y(32) h(80) zero(16)
            int d = row & 31;
            if (kk < 32)       v = (row < 32 ? fw : gw)[(l * 32 + d) * 32 + kk];
            else if (kk < 112) v = (row < 32 ? cfw : cgw)[(l * 32 + d) * 80 + (kk - 32)];
            else               v = 0.f;
        } else {                                   // out 1x1: tile = mt
            int o3 = o - G4_OFF;
            int mt = o3 >> 9, li = o3 & 511;
            int lane = li >> 3, j = li & 7;
            int m = lane & 15, q = lane >> 4;
            int r = mt * 16 + m, d = q * 8 + j;
            v = ow[(l * 32 + r) * 32 + d];
        }
        wpk[idx] = (unsigned short)f2bfbits(v);
    } else if (idx < NLAYERS * WPL2 + 16 * 512) {  // e1pk: 16 m-tiles, K=32
        int o = idx - NLAYERS * WPL2;
        int mt = o >> 9, li = o & 511;
        int lane = li >> 3, j = li & 7;
        int m = lane & 15, q = lane >> 4;
        int s = mt * 16 + m, c = q * 8 + j;
        e1pk[o] = (unsigned short)f2bfbits(e1[s * RC + c]);
    } else {                                       // e2pk: (mt*8+kf) tiles
        int o = idx - NLAYERS * WPL2 - 16 * 512;   // < 65536 exactly
        int t = o >> 9, li = o & 511;
        int mt = t >> 3, kf = t & 7;
        int lane = li >> 3, j = li & 7;
        int m = lane & 15, q = lane >> 4;
        int cls = mt * 16 + m, k = kf * 32 + q * 8 + j;
        e2pk[o] = (unsigned short)f2bfbits(e2[cls * SC + k]);
    }
}

// ---- all 40 layers, MFMA. Residual fp32 in regs; LDS holds bf16 activations.
__global__ __launch_bounds__(256, 3) void fused_mfma_kernel(
    const float* __restrict__ x, const float* __restrict__ h,
    const float* __restrict__ sw, const unsigned short* __restrict__ wpk,
    float* __restrict__ skip_out)
{
    __shared__ unsigned short act[TILE_W * AS];    // 43,008 B -> 3 blocks/CU

    const int tid  = threadIdx.x;
    const int lane = tid & 63;
    const int wave = tid >> 6;
    const int quad = lane >> 4;
    const int l16  = lane & 15;
    const int b    = blockIdx.x / NT;
    const int tile = blockIdx.x % NT;
    const int tbase = tile * TILE_OUT - HALO;
    const bool tile0 = (tile == 0);

    // stage h as bf16 (clamped both edges) + zero the K-pad region
    {
        const int col = tid & 127;
        const int half = tid >> 7;
        const int gtc = min(max(tbase + col, 0), T_DIM - 1);
        const float* hp = h + (size_t)b * COND * T_DIM + gtc;
        for (int j = half; j < COND; j += 2)
            act[col * AS + CH_H + j] = (unsigned short)f2bfbits(hp[(size_t)j * T_DIM]);
        *(uint4*)(act + col * AS + CH_ZERO + half * 8) = make_uint4(0u, 0u, 0u, 0u);
    }

    // residual registers: lane owns (ch = mt*16+quad*4+r, col = wave*32+nt*16+l16)
    const f32x4 zero4 = {0.f, 0.f, 0.f, 0.f};
    float xv[2], mskv[2];
    float swr[2][4];
    f32x4 res[2][2];

#pragma unroll
    for (int nt = 0; nt < 2; nt++) {
        int gt = tbase + wave * 32 + nt * 16 + l16;
        int gx = min(max(gt, 0), T_DIM - 1);
        float v = x[(size_t)b * T_DIM + gx];
        mskv[nt] = (gt >= 0) ? 1.f : 0.f;
        xv[nt] = v * mskv[nt];
    }
#pragma unroll
    for (int mt = 0; mt < 2; mt++)
#pragma unroll
        for (int r = 0; r < 4; r++)
            swr[mt][r] = sw[mt * 16 + quad * 4 + r];
#pragma unroll
    for (int mt = 0; mt < 2; mt++)
#pragma unroll
        for (int nt = 0; nt < 2; nt++) {
#pragma unroll
            for (int r = 0; r < 4; r++) res[mt][nt][r] = swr[mt][r] * xv[nt];
            const int c = wave * 32 + nt * 16 + l16;
            const int ch0 = mt * 16 + quad * 4;
            unsigned h0 = pk2(res[mt][nt][0], res[mt][nt][1]);
            unsigned h1 = pk2(res[mt][nt][2], res[mt][nt][3]);
            *(uint2*)(act + c * AS + CH_RH + ch0) = make_uint2(h0, h1);
        }
    __syncthreads();

    const unsigned short* wl = wpk;
    for (int l = 0; l < NLAYERS; l++, wl += WPL2) {
        // conv B-frags (prv needs col-1 -> cross-wave; read BEFORE barrier)
        bf16x8 bc[2][2];   // [ks: prv/cur][nt]
#pragma unroll
        for (int nt = 0; nt < 2; nt++) {
            const int c = wave * 32 + nt * 16 + l16;
            const int cp = max(c - 1, 0);
            bc[0][nt] = *(const bf16x8*)(act + cp * AS + CH_RH + quad * 8);
            bc[1][nt] = *(const bf16x8*)(act + c  * AS + CH_RH + quad * 8);
        }
        __syncthreads();   // A: conv reads done before this layer's resb writes

        // GEMM1: y[32] = Wdil . [prv;cur]
        f32x4 acc1[2][2];
#pragma unroll
        for (int mt = 0; mt < 2; mt++)
#pragma unroll
            for (int nt = 0; nt < 2; nt++) acc1[mt][nt] = zero4;
#pragma unroll
        for (int ks = 0; ks < 2; ks++)
#pragma unroll
            for (int mt = 0; mt < 2; mt++) {
                bf16x8 a = *(const bf16x8*)(wl + (mt * 2 + ks) * 512 + lane * 8);
#pragma unroll
                for (int nt = 0; nt < 2; nt++)
                    acc1[mt][nt] = mfma16(a, bc[ks][nt], acc1[mt][nt]);
            }

        // pack y -> CH_Z
#pragma unroll
        for (int mt = 0; mt < 2; mt++)
#pragma unroll
            for (int nt = 0; nt < 2; nt++) {
                const int c = wave * 32 + nt * 16 + l16;
                unsigned p0 = pk2(acc1[mt][nt][0], acc1[mt][nt][1]);
                unsigned p1 = pk2(acc1[mt][nt][2], acc1[mt][nt][3]);
                *(uint2*)(act + c * AS + CH_Z + mt * 16 + quad * 4) = make_uint2(p0, p1);
            }

        // GEMM2: [f;g] = W . [y | h | 0]  (M=64, K=128; LDS rows contiguous)
        f32x4 acc2[4][2];
#pragma unroll
        for (int mt = 0; mt < 4; mt++)
#pragma unroll
            for (int nt = 0; nt < 2; nt++) acc2[mt][nt] = zero4;
#pragma unroll
        for (int kt = 0; kt < 4; kt++) {
            bf16x8 bb[2];
#pragma unroll
            for (int nt = 0; nt < 2; nt++) {
                const int c = wave * 32 + nt * 16 + l16;
                bb[nt] = *(const bf16x8*)(act + c * AS + CH_Z + kt * 32 + quad * 8);
            }
#pragma unroll
            for (int mt = 0; mt < 4; mt++) {
                bf16x8 a = *(const bf16x8*)(wl + G2_OFF + (mt * 4 + kt) * 512 + lane * 8);
#pragma unroll
                for (int nt = 0; nt < 2; nt++)
                    acc2[mt][nt] = mfma16(a, bb[nt], acc2[mt][nt]);
            }
        }

        // glue: z = tanh(f)*sigmoid(g)  (inf-safe, v_rcp) ; pack z -> CH_Z
#pragma unroll
        for (int mt = 0; mt < 2; mt++)
#pragma unroll
            for (int nt = 0; nt < 2; nt++) {
                const int c = wave * 32 + nt * 16 + l16;
                float z[4];
#pragma unroll
                for (int r = 0; r < 4; r++) {
                    float fa = acc2[mt][nt][r];
                    float ga = acc2[mt + 2][nt][r];
                    float ev = __expf(2.f * fa);
                    float th = 1.f - 2.f * __builtin_amdgcn_rcpf(ev + 1.f);
                    float sg = __builtin_amdgcn_rcpf(1.f + __expf(-ga));
                    z[r] = th * sg;
                }
                *(uint2*)(act + c * AS + CH_Z + mt * 16 + quad * 4) =
                    make_uint2(pk2(z[0], z[1]), pk2(z[2], z[3]));
            }

        // GEMM4: out[32] = Wout . z
        f32x4 acc4[2][2];
#pragma unroll
        for (int mt = 0; mt < 2; mt++)
#pragma unroll
            for (int nt = 0; nt < 2; nt++) acc4[mt][nt] = zero4;
        bf16x8 bz[2];
#pragma unroll
        for (int nt = 0; nt < 2; nt++) {
            const int c = wave * 32 + nt * 16 + l16;
            bz[nt] = *(const bf16x8*)(act + c * AS + CH_Z + quad * 8);
        }
#pragma unroll
        for (int mt = 0; mt < 2; mt++) {
            bf16x8 a = *(const bf16x8*)(wl + G4_OFF + mt * 512 + lane * 8);
#pragma unroll
            for (int nt = 0; nt < 2; nt++)
                acc4[mt][nt] = mfma16(a, bz[nt], acc4[mt][nt]);
        }

        // residual update (fp32 regs) + resb write; mask only on tile 0
#pragma unroll
        for (int mt = 0; mt < 2; mt++)
#pragma unroll
            for (int nt = 0; nt < 2; nt++) {
                const int c = wave * 32 + nt * 16 + l16;
                const int ch0 = mt * 16 + quad * 4;
                f32x4 nr = res[mt][nt] + acc4[mt][nt];
                if (tile0 && wave < 2) nr = nr * mskv[nt];   // block/wave-uniform branch
                res[mt][nt] = nr;
                unsigned h0 = pk2(nr[0], nr[1]);
                unsigned h1 = pk2(nr[2], nr[3]);
                *(uint2*)(act + c * AS + CH_RH + ch0) = make_uint2(h0, h1);
            }
        __syncthreads();   // B: resb writes visible before next layer's reads
    }

    // epilogue: skip = res_final - res_0 (cols >= HALO, in range)
#pragma unroll
    for (int mt = 0; mt < 2; mt++)
#pragma unroll
        for (int nt = 0; nt < 2; nt++) {
            const int c = wave * 32 + nt * 16 + l16;
            const int gt = tbase + c;
            if (c >= HALO && gt < T_DIM) {
#pragma unroll
                for (int r = 0; r < 4; r++) {
                    const int ch = mt * 16 + quad * 4 + r;
                    skip_out[((size_t)b * RC + ch) * T_DIM + gt] =
                        res[mt][nt][r] - swr[mt][r] * xv[nt];
                }
            }
        }
}

// ---- end: relu->e1->relu->e2 with MFMA (bf16). Block = 64 cols, M=256.
__global__ __launch_bounds__(256) void end_kernel(
    const float* __restrict__ skip,          // [B,32,T]
    const unsigned short* __restrict__ e1pk, // A-frags [16 mt][512]
    const unsigned short* __restrict__ e2pk, // A-frags [16 mt * 8 kf][512]
    float* __restrict__ outp)                // [B][256][T]
{
    __shared__ unsigned short sk_s[64 * 40];    // [col][ch], pad 32->40
    __shared__ unsigned short e_s[64 * 264];    // [col][s], pad 256->264

    const int tid  = threadIdx.x;
    const int lane = tid & 63;
    const int wave = tid >> 6;
    const int quad = lane >> 4;
    const int l16  = lane & 15;
    const int b  = blockIdx.x >> 8;
    const int t0 = (blockIdx.x & 255) * 64;

    // stage relu(skip) -> bf16 [col][ch]
    {
        const int col = tid & 63;
        const int cg = tid >> 6;           // 4 channel groups of 8
        const float* sp = skip + ((size_t)b * RC + cg * 8) * T_DIM + t0 + col;
        float v[8];
#pragma unroll
        for (int k = 0; k < 8; k++)
            v[k] = fmaxf(sp[(size_t)k * T_DIM], 0.f);
        unsigned u0 = pk2(v[0], v[1]), u1 = pk2(v[2], v[3]);
        unsigned u2 = pk2(v[4], v[5]), u3 = pk2(v[6], v[7]);
        *(uint2*)(sk_s + col * 40 + cg * 8)     = make_uint2(u0, u1);
        *(uint2*)(sk_s + col * 40 + cg * 8 + 4) = make_uint2(u2, u3);
    }
    __syncthreads();

    // phase 1: e[256 s][64 col] = relu(e1 . sk) ; wave handles 4 m-tiles
    {
        bf16x8 bb[4];
#pragma unroll
        for (int ntl = 0; ntl < 4; ntl++)
            bb[ntl] = *(const bf16x8*)(sk_s + (ntl * 16 + l16) * 40 + quad * 8);
#pragma unroll
        for (int mtl = 0; mtl < 4; mtl++) {
            const int mt = wave * 4 + mtl;
            bf16x8 a = *(const bf16x8*)(e1pk + mt * 512 + lane * 8);
            f32x4 acc[4];
#pragma unroll
            for (int ntl = 0; ntl < 4; ntl++) {
                acc[ntl] = mfma16(a, bb[ntl], (f32x4){0.f, 0.f, 0.f, 0.f});
            }
#pragma unroll
            for (int ntl = 0; ntl < 4; ntl++) {
                const int col = ntl * 16 + l16;
                unsigned p0 = pk2(fmaxf(acc[ntl][0], 0.f), fmaxf(acc[ntl][1], 0.f));
                unsigned p1 = pk2(fmaxf(acc[ntl][2], 0.f), fmaxf(acc[ntl][3], 0.f));
                *(uint2*)(e_s + col * 264 + mt * 16 + quad * 4) = make_uint2(p0, p1);
            }
        }
    }
    __syncthreads();

    // phase 2: logits[256 cls][64 col] = e2 . e ; wave: 4 m-tiles x 4 n x 8 k
    {
        f32x4 acc[4][4];
#pragma unroll
        for (int mtl = 0; mtl < 4; mtl++)
#pragma unroll
            for (int ntl = 0; ntl < 4; ntl++) acc[mtl][ntl] = (f32x4){0.f, 0.f, 0.f, 0.f};

        for (int kf = 0; kf < 8; kf++) {
            bf16x8 bb[4];
#pragma unroll
            for (int ntl = 0; ntl < 4; ntl++)
                bb[ntl] = *(const bf16x8*)(e_s + (ntl * 16 + l16) * 264 + kf * 32 + quad * 8);
#pragma unroll
            for (int mtl = 0; mtl < 4; mtl++) {
                const int mt = wave * 4 + mtl;
                bf16x8 a = *(const bf16x8*)(e2pk + (mt * 8 + kf) * 512 + lane * 8);
#pragma unroll
                for (int ntl = 0; ntl < 4; ntl++)
                    acc[mtl][ntl] = mfma16(a, bb[ntl], acc[mtl][ntl]);
            }
        }

#pragma unroll
        for (int mtl = 0; mtl < 4; mtl++)
#pragma unroll
            for (int ntl = 0; ntl < 4; ntl++) {
                const int cls0 = (wave * 4 + mtl) * 16 + quad * 4;
                const int col = ntl * 16 + l16;
#pragma unroll
                for (int r = 0; r < 4; r++)
                    outp[((size_t)b * CLASSES + cls0 + r) * T_DIM + t0 + col] =
                        acc[mtl][ntl][r];
            }
    }
}

extern "C" void kernel_launch(void* const* d_in, const int* in_sizes, int n_in,
                              void* d_out, int out_size, void* d_ws, size_t ws_size,
                              hipStream_t stream) {
    const float* x   = (const float*)d_in[0];
    const float* h   = (const float*)d_in[1];
    const float* sw  = (const float*)d_in[2];
    const float* dw  = (const float*)d_in[3];
    const float* fw  = (const float*)d_in[4];
    const float* gw  = (const float*)d_in[5];
    const float* cfw = (const float*)d_in[6];
    const float* cgw = (const float*)d_in[7];
    const float* ow  = (const float*)d_in[8];
    const float* e1  = (const float*)d_in[9];
    const float* e2  = (const float*)d_in[10];
    float* out = (float*)d_out;

    const size_t SKIP_N = (size_t)B_DIM * RC * T_DIM;   // 2,097,152 floats
    float* skip = (float*)d_ws;
    unsigned short* wpk  = (unsigned short*)(skip + SKIP_N);
    unsigned short* e1pk = wpk + (size_t)NLAYERS * WPL2;
    unsigned short* e2pk = e1pk + 16 * 512;

    // 450,560 + 8,192 + 65,536 = 524,288 -> 2048 blocks exactly
    pack_kernel<<<2048, 256, 0, stream>>>(dw, fw, gw, cfw, cgw, ow, e1, e2,
                                          wpk, e1pk, e2pk);

    fused_mfma_kernel<<<B_DIM * NT, 256, 0, stream>>>(x, h, sw, wpk, skip);

    end_kernel<<<B_DIM * 256, 256, 0, stream>>>(skip, e1pk, e2pk, out);
}